// Round 8
// baseline (438.216 us; speedup 1.0000x reference)
//
#include <hip/hip_runtime.h>

#define MM 64
#define NN 16
#define DDIM 300
#define FNUM 768
#define SURF_LL 4
#define CTX_LL 50
#define DOC_LL 100
#define BODY_LL 200
#define NHEADS 5
#define HDIM 60

// GEMM dims for conv_mc:  C[GM][GN] = A[GM][GK] * B^T, K padded 1500->1536
#define GM 2944   // 64 m * 46 t
#define GK 1536
#define GN 768

typedef unsigned short u16;
typedef unsigned int u32;
typedef __attribute__((ext_vector_type(8))) short short8;
typedef __attribute__((ext_vector_type(4))) float f32x4;

// ---- workspace layout (float offsets) ----
#define OFF_MSG    0                    // mention emb [256][300]
#define OFF_CTX2G  76800                // contexts_ids emb [3200][300]
#define OFF_CANDG  1036800              // men2cands emb [1024][300]
#define OFF_MS     1344000              // ms [64][768]
#define OFF_MC     1393152              // mc [64][768] (atomic mean accum)
#define OFF_PV0    1442304              // [16][5][2][60]
#define OFF_PV1    1451904              // [16][5][4][60]
#define OFF_ASC    1471104              // [16]
#define OFF_LATT   1471120              // [64][16]
#define OFF_ABF    1472144              // u16[GM*GK]
#define OFF_WTMC   (OFF_ABF + GM*GK/2)  // u16[GN*GK]
#define OFF_WTMS   (OFF_WTMC + GN*GK/2) // float[600*768]
#define OFF_P      (OFF_WTMS + 600*768) // attn P [160][20000]

__device__ __forceinline__ u16 f2bf(float x) {
  union { float f; u32 u; } v; v.f = x;
  u32 r = v.u + 0x7FFFu + ((v.u >> 16) & 1u);
  return (u16)(r >> 16);
}

// ---------------------------------------------------------------------------
// MEGA-PREP: gather embeddings + zero mc + im2col bf16 + weight repacks.
__global__ __launch_bounds__(256) void mega_prep_kernel(
    const float* __restrict__ embed,
    const int* __restrict__ mention_vec,
    const int* __restrict__ context_vec,
    const int* __restrict__ contexts_ids,
    const int* __restrict__ men2cands,
    const float* __restrict__ Wmc,
    const float* __restrict__ Wms,
    float* __restrict__ dst, float* __restrict__ mc,
    u32* __restrict__ Abf, u32* __restrict__ WTmc, float* __restrict__ WTms) {
  int bid = blockIdx.x;
  if (bid < 5250) {
    int e = bid * 256 + threadIdx.x;
    int row = e / DDIM;
    int col = e - row * DDIM;
    int tok;
    if (row < 256)       tok = mention_vec[row];
    else if (row < 3456) tok = contexts_ids[row - 256];
    else                 tok = men2cands[row - 3456];
    dst[e] = embed[(size_t)tok * DDIM + col];
  } else if (bid < 5442) {
    mc[(bid - 5250) * 256 + threadIdx.x] = 0.f;
  } else if (bid < 14274) {
    int idx = (bid - 5442) * 256 + threadIdx.x;  // one u32 = 2 bf16
    int r = idx / (GK / 2);
    int kp = idx - r * (GK / 2);
    int k = kp * 2;
    int m = r / 46, t = r - m * 46;
    u32 out = 0;
#pragma unroll
    for (int j = 0; j < 2; j++) {
      int kj = k + j;
      u16 h = 0;
      if (kj < 1500) {
        int tap = kj / 300;
        int d = kj - tap * 300;
        int tok = context_vec[m * CTX_LL + t + tap];
        h = f2bf(embed[(size_t)tok * DDIM + d]);
      }
      out |= (u32)h << (16 * j);
    }
    Abf[idx] = out;
  } else if (bid < 16578) {
    int idx = (bid - 14274) * 256 + threadIdx.x;
    int n = idx / (GK / 2);
    int kp = idx - n * (GK / 2);
    int k = kp * 2;
    u32 out = 0;
#pragma unroll
    for (int j = 0; j < 2; j++) {
      int kj = k + j;
      u16 h = 0;
      if (kj < 1500) {
        int tap = kj / 300;
        int d = kj - tap * 300;
        h = f2bf(Wmc[(size_t)n * 1500 + d * 5 + tap]);
      }
      out |= (u32)h << (16 * j);
    }
    WTmc[idx] = out;
  } else {
    int idx = (bid - 16578) * 256 + threadIdx.x;  // 600*768
    int k = idx / FNUM;
    int f = idx - k * FNUM;
    WTms[idx] = Wms[(size_t)f * 600 + k];
  }
}

// ---------------------------------------------------------------------------
// bf16 MFMA GEMM with fused relu+mean epilogue (atomicAdd into mc).
__global__ __launch_bounds__(256) void conv_gemm_kernel(
    const u16* __restrict__ A,    // [GM][GK] bf16
    const u16* __restrict__ B,    // [GN][GK] bf16 (n-major)
    const float* __restrict__ bias,
    float* __restrict__ mc) {     // [64][768]
  int bn = blockIdx.x, bm = blockIdx.y;
  __shared__ u16 As[64][72];
  __shared__ u16 Bs[64][72];
  int tid = threadIdx.x;
  int w = tid >> 6, lane = tid & 63;
  int wr = w >> 1, wc = w & 1;
  int lg = lane >> 4, lm = lane & 15;
  f32x4 acc[2][2];
#pragma unroll
  for (int i = 0; i < 2; i++)
#pragma unroll
    for (int j = 0; j < 2; j++) acc[i][j] = (f32x4)0.f;
  int c0row = tid >> 3, ck = (tid & 7) * 8;
  const u16* Ag = A + (size_t)(bm * 64) * GK;
  const u16* Bg = B + (size_t)(bn * 64) * GK;
  for (int kt = 0; kt < GK / 64; kt++) {
    int k0 = kt * 64;
    uint4 av0 = *(const uint4*)(Ag + (size_t)c0row * GK + k0 + ck);
    uint4 av1 = *(const uint4*)(Ag + (size_t)(c0row + 32) * GK + k0 + ck);
    uint4 bv0 = *(const uint4*)(Bg + (size_t)c0row * GK + k0 + ck);
    uint4 bv1 = *(const uint4*)(Bg + (size_t)(c0row + 32) * GK + k0 + ck);
    __syncthreads();
    *(uint4*)&As[c0row][ck] = av0;
    *(uint4*)&As[c0row + 32][ck] = av1;
    *(uint4*)&Bs[c0row][ck] = bv0;
    *(uint4*)&Bs[c0row + 32][ck] = bv1;
    __syncthreads();
#pragma unroll
    for (int kk = 0; kk < 2; kk++) {
      short8 af0 = *(const short8*)&As[wr * 32 + lm][kk * 32 + lg * 8];
      short8 af1 = *(const short8*)&As[wr * 32 + 16 + lm][kk * 32 + lg * 8];
      short8 bf0 = *(const short8*)&Bs[wc * 32 + lm][kk * 32 + lg * 8];
      short8 bf1 = *(const short8*)&Bs[wc * 32 + 16 + lm][kk * 32 + lg * 8];
      acc[0][0] = __builtin_amdgcn_mfma_f32_16x16x32_bf16(af0, bf0, acc[0][0], 0, 0, 0);
      acc[0][1] = __builtin_amdgcn_mfma_f32_16x16x32_bf16(af0, bf1, acc[0][1], 0, 0, 0);
      acc[1][0] = __builtin_amdgcn_mfma_f32_16x16x32_bf16(af1, bf0, acc[1][0], 0, 0, 0);
      acc[1][1] = __builtin_amdgcn_mfma_f32_16x16x32_bf16(af1, bf1, acc[1][1], 0, 0, 0);
    }
  }
#pragma unroll
  for (int mf = 0; mf < 2; mf++)
#pragma unroll
    for (int nf = 0; nf < 2; nf++) {
      int col = bn * 64 + wc * 32 + nf * 16 + lm;
      float bb = bias[col];
      int base = bm * 64 + wr * 32 + mf * 16 + lg * 4;
      int mcur = base / 46;
      float s = 0.f;
#pragma unroll
      for (int r = 0; r < 4; r++) {
        float v = fmaxf(acc[mf][nf][r] + bb, 0.f) * (1.0f / 46.0f);
        int mm = (base + r) / 46;
        if (mm != mcur) { atomicAdd(&mc[mcur * FNUM + col], s); s = 0.f; mcur = mm; }
        s += v;
      }
      atomicAdd(&mc[mcur * FNUM + col], s);
    }
}

// ---------------------------------------------------------------------------
// scores dir1 (q=body 200, k=doc 100): single-pass, K[100][61]+Q[32][61] LDS.
__device__ __forceinline__ void scores1_body(
    const float* __restrict__ embed, const int* __restrict__ doc_vec,
    const int* __restrict__ body_vec, float* __restrict__ P, int b,
    float* __restrict__ smem) {
  constexpr int Lq = 200, Lk = 100, KPL = 2;
  int qt = b / 80;
  int rem = b - qt * 80;
  int n = rem / 5, h = rem - n * 5;
  const int* qids = body_vec + n * BODY_LL;
  const int* kids = doc_vec;
  float* Ks = smem;             // [100][61]
  float* Qs = smem + 100 * 61;  // [32][61]
  for (int idx = threadIdx.x; idx < Lk * 15; idx += 256) {
    int r = idx / 15, c = idx - r * 15;
    float4 v = *(const float4*)(embed + (size_t)kids[r] * DDIM + h * HDIM + c * 4);
    float* dp = Ks + r * 61 + c * 4;
    dp[0] = v.x; dp[1] = v.y; dp[2] = v.z; dp[3] = v.w;
  }
  for (int idx = threadIdx.x; idx < 32 * 15; idx += 256) {
    int r = idx / 15, c = idx - r * 15;
    int q = qt * 32 + r; if (q >= Lq) q = Lq - 1;
    float4 v = *(const float4*)(embed + (size_t)qids[q] * DDIM + h * HDIM + c * 4);
    float* dp = Qs + r * 61 + c * 4;
    dp[0] = v.x; dp[1] = v.y; dp[2] = v.z; dp[3] = v.w;
  }
  __syncthreads();
  int w = threadIdx.x >> 6, lane = threadIdx.x & 63;
  float acc[8][KPL];
#pragma unroll
  for (int i = 0; i < 8; i++)
#pragma unroll
    for (int j = 0; j < KPL; j++) acc[i][j] = 0.f;
  for (int d = 0; d < HDIM; d++) {
    float kv[KPL];
#pragma unroll
    for (int j = 0; j < KPL; j++) {
      int kk = lane + 64 * j; if (kk >= Lk) kk = Lk - 1;
      kv[j] = Ks[kk * 61 + d];
    }
#pragma unroll
    for (int i = 0; i < 8; i++) {
      float qv = Qs[(w * 8 + i) * 61 + d];
#pragma unroll
      for (int j = 0; j < KPL; j++) acc[i][j] += qv * kv[j];
    }
  }
  const float scale = 0.12909944487358056f;  // 1/sqrt(60)
#pragma unroll
  for (int i = 0; i < 8; i++) {
    int q = qt * 32 + w * 8 + i;
    float mx = -1e30f;
#pragma unroll
    for (int j = 0; j < KPL; j++)
      if (lane + 64 * j < Lk) mx = fmaxf(mx, acc[i][j]);
#pragma unroll
    for (int o = 32; o >= 1; o >>= 1) mx = fmaxf(mx, __shfl_xor(mx, o));
    float mxs = mx * scale;
    float p[KPL];
    float s = 0.f;
#pragma unroll
    for (int j = 0; j < KPL; j++) {
      p[j] = (lane + 64 * j < Lk) ? __expf(acc[i][j] * scale - mxs) : 0.f;
      s += p[j];
    }
#pragma unroll
    for (int o = 32; o >= 1; o >>= 1) s += __shfl_xor(s, o);
    float inv = 1.0f / s;
    if (q < Lq) {
      float* rowp = P + (size_t)((n * 2 + 1) * NHEADS + h) * 20000 + q * Lk;
#pragma unroll
      for (int j = 0; j < KPL; j++) {
        int kk = lane + 64 * j;
        if (kk < Lk) rowp[kk] = p[j] * inv;
      }
    }
  }
}

// scores dir0 (q=doc 100, k=body 200): TWO-PASS K staging into the same
// [100][61] buffer; acc[8][4] persists across passes (VGPR-lean scalar loop).
// k index = p*100 + j*64 + lane (j=1 valid for lane<36).
__device__ __forceinline__ void scores0_body(
    const float* __restrict__ embed, const int* __restrict__ doc_vec,
    const int* __restrict__ body_vec, float* __restrict__ P, int b,
    float* __restrict__ smem) {
  constexpr int Lq = 100, Lk = 200;
  int qt = b / 80;
  int rem = b - qt * 80;
  int n = rem / 5, h = rem - n * 5;
  const int* qids = doc_vec;
  const int* kids = body_vec + n * BODY_LL;
  float* Ks = smem;             // [100][61] (per pass)
  float* Qs = smem + 100 * 61;  // [32][61]
  for (int idx = threadIdx.x; idx < 32 * 15; idx += 256) {
    int r = idx / 15, c = idx - r * 15;
    int q = qt * 32 + r; if (q >= Lq) q = Lq - 1;
    float4 v = *(const float4*)(embed + (size_t)qids[q] * DDIM + h * HDIM + c * 4);
    float* dp = Qs + r * 61 + c * 4;
    dp[0] = v.x; dp[1] = v.y; dp[2] = v.z; dp[3] = v.w;
  }
  int w = threadIdx.x >> 6, lane = threadIdx.x & 63;
  int k1 = (lane < 36) ? (64 + lane) : 99;  // clamped 2nd k within a pass
  float acc[8][4];
#pragma unroll
  for (int i = 0; i < 8; i++)
#pragma unroll
    for (int j = 0; j < 4; j++) acc[i][j] = 0.f;
  for (int p = 0; p < 2; p++) {
    __syncthreads();  // Q ready (p=0) / pass-0 readers done (p=1)
    for (int idx = threadIdx.x; idx < 100 * 15; idx += 256) {
      int r = idx / 15, c = idx - r * 15;
      float4 v = *(const float4*)(embed + (size_t)kids[p * 100 + r] * DDIM + h * HDIM + c * 4);
      float* dp = Ks + r * 61 + c * 4;
      dp[0] = v.x; dp[1] = v.y; dp[2] = v.z; dp[3] = v.w;
    }
    __syncthreads();
    for (int d = 0; d < HDIM; d++) {
      float kv0 = Ks[lane * 61 + d];
      float kv1 = Ks[k1 * 61 + d];
#pragma unroll
      for (int i = 0; i < 8; i++) {
        float qv = Qs[(w * 8 + i) * 61 + d];
        acc[i][p * 2 + 0] += qv * kv0;
        acc[i][p * 2 + 1] += qv * kv1;
      }
    }
  }
  const float scale = 0.12909944487358056f;  // 1/sqrt(60)
  bool v1 = (lane < 36);
#pragma unroll
  for (int i = 0; i < 8; i++) {
    int q = qt * 32 + w * 8 + i;
    float mx = fmaxf(acc[i][0], acc[i][2]);
    if (v1) mx = fmaxf(mx, fmaxf(acc[i][1], acc[i][3]));
#pragma unroll
    for (int o = 32; o >= 1; o >>= 1) mx = fmaxf(mx, __shfl_xor(mx, o));
    float mxs = mx * scale;
    float p0 = __expf(acc[i][0] * scale - mxs);
    float p1 = v1 ? __expf(acc[i][1] * scale - mxs) : 0.f;
    float p2 = __expf(acc[i][2] * scale - mxs);
    float p3 = v1 ? __expf(acc[i][3] * scale - mxs) : 0.f;
    float s = p0 + p1 + p2 + p3;
#pragma unroll
    for (int o = 32; o >= 1; o >>= 1) s += __shfl_xor(s, o);
    float inv = 1.0f / s;
    if (q < Lq) {
      float* rowp = P + (size_t)((n * 2 + 0) * NHEADS + h) * 20000 + q * Lk;
      rowp[lane] = p0 * inv;
      rowp[100 + lane] = p2 * inv;
      if (v1) {
        rowp[64 + lane] = p1 * inv;
        rowp[164 + lane] = p3 * inv;
      }
    }
  }
}

// ---------------------------------------------------------------------------
// conv_ms body (no LDS).
__device__ __forceinline__ void conv_ms_body(
    const float* __restrict__ msg, const float* __restrict__ WT,
    const float* __restrict__ B, float* __restrict__ ms, int b) {
  int m = b / 3, fi = b - m * 3;
  int f = fi * 256 + threadIdx.x;
  const float* x = msg + m * SURF_LL * DDIM;
  float a0 = 0.f, a1 = 0.f, a2 = 0.f;
  for (int d = 0; d < DDIM; d++) {
    float v0 = x[d], v1 = x[DDIM + d], v2 = x[2 * DDIM + d], v3 = x[3 * DDIM + d];
    float wA = WT[(size_t)(2 * d) * FNUM + f];
    float wB = WT[(size_t)(2 * d + 1) * FNUM + f];
    a0 += v0 * wA + v1 * wB;
    a1 += v1 * wA + v2 * wB;
    a2 += v2 * wA + v3 * wB;
  }
  float bb = B[f];
  float r = fmaxf(a0 + bb, 0.f) + fmaxf(a1 + bb, 0.f) + fmaxf(a2 + bb, 0.f);
  ms[m * FNUM + f] = r * (1.0f / 3.0f);
}

// tok + ctxv fused (cand via 16-lane-broadcast global reads; ctx tile in LDS).
__device__ __forceinline__ void tokctxv_body(
    const float* __restrict__ candg, const float* __restrict__ ctx2g,
    float* __restrict__ local_att, int m, float* __restrict__ smem) {
  float* ctx   = smem;          // [16][300]
  float* tokb  = smem + 4800;   // [16][17]
  float* tkmx  = smem + 5072;   // [64] (50 used)
  float* pp    = smem + 5136;   // [64]
  float* sctxv = smem + 5200;   // [300]
  int tid = threadIdx.x;
  int nI = tid >> 4, tt = tid & 15;
  const float4* ca = (const float4*)(candg + (size_t)(m * NN + nI) * DDIM);
  for (int tile = 0; tile < 4; tile++) {
    int cbase = tile * 16;
    __syncthreads();
    for (int i = tid; i < 16 * DDIM; i += 256) {
      int rr = i / DDIM, cc = i - rr * DDIM;
      int t = cbase + rr;
      ctx[rr * DDIM + cc] = (t < CTX_LL) ? ctx2g[(size_t)(m * CTX_LL + t) * DDIM + cc] : 0.f;
    }
    __syncthreads();
    const float4* cb = (const float4*)(ctx + tt * DDIM);
    float dsum = 0.f;
#pragma unroll
    for (int c = 0; c < 75; c++) {
      float4 a = ca[c], b = cb[c];
      dsum += a.x * b.x + a.y * b.y + a.z * b.z + a.w * b.w;
    }
    tokb[nI * 17 + tt] = dsum;
    __syncthreads();
    if (tid < 16) {
      float mx = -1e30f;
      for (int nn = 0; nn < NN; nn++) mx = fmaxf(mx, tokb[nn * 17 + tid]);
      int t = cbase + tid;
      if (t < CTX_LL) tkmx[t] = mx;
    }
  }
  __syncthreads();
  if (tid < 64) {
    float v = (tid < CTX_LL) ? tkmx[tid] : -1e30f;
    float mx = v;
#pragma unroll
    for (int o = 32; o >= 1; o >>= 1) mx = fmaxf(mx, __shfl_xor(mx, o));
    float e = (tid < CTX_LL) ? expf(v - mx) : 0.f;
    float s = e;
#pragma unroll
    for (int o = 32; o >= 1; o >>= 1) s += __shfl_xor(s, o);
    pp[tid] = e / s;
  }
  __syncthreads();
  for (int d = tid; d < DDIM; d += 256) {
    float acc = 0.f;
    for (int t = 0; t < CTX_LL; t++)
      acc += pp[t] * ctx2g[(size_t)(m * CTX_LL + t) * DDIM + d];
    sctxv[d] = acc;
  }
  __syncthreads();
  int j = tid & 15;
  const float* crow = candg + (size_t)(m * NN + nI) * DDIM;
  float dd = 0.f;
  for (int i = j; i < DDIM; i += 16) dd += crow[i] * sctxv[i];
#pragma unroll
  for (int o = 8; o >= 1; o >>= 1) dd += __shfl_xor(dd, o);
  if (j == 0) local_att[m * NN + nI] = dd;
}

// MEGA-MID: [0,64) tok+ctxv ; [64,384) scores dir0 (two-pass) ;
// [384,944) scores dir1 ; [944,1136) conv_ms (no LDS, tail fillers).
// smem 8052 floats = 32.2 KB -> 4 blocks/CU uniform.
__global__ __launch_bounds__(256) void mega_mid_kernel(
    const float* __restrict__ embed,
    const int* __restrict__ doc_vec,
    const int* __restrict__ body_vec,
    const float* __restrict__ msg,
    const float* __restrict__ WTms,
    const float* __restrict__ Bms,
    const float* __restrict__ candg,
    const float* __restrict__ ctx2g,
    float* __restrict__ ms,
    float* __restrict__ P,
    float* __restrict__ local_att) {
  __shared__ float smem[(100 + 32) * 61];  // 8052 floats
  int bid = blockIdx.x;
  if (bid < 64) {
    tokctxv_body(candg, ctx2g, local_att, bid, smem);
  } else if (bid < 384) {
    scores0_body(embed, doc_vec, body_vec, P, bid - 64, smem);
  } else if (bid < 944) {
    scores1_body(embed, doc_vec, body_vec, P, bid - 384, smem);
  } else {
    conv_ms_body(msg, WTms, Bms, ms, bid - 944);
  }
}

// ---------------------------------------------------------------------------
// PV + max-pool over q, both dirs merged (unchanged since R4).
__global__ __launch_bounds__(256) void attn_pv_kernel(
    const float* __restrict__ embed,
    const int* __restrict__ doc_vec,
    const int* __restrict__ body_vec,
    const float* __restrict__ P,
    float* __restrict__ pv0,   // [16][5][2][60]
    float* __restrict__ pv1) { // [16][5][4][60]
  int bid = blockIdx.x;
  int dir, pt, n, h;
  if (bid < 160) { dir = 0; h = bid % 5; n = (bid / 5) % 16; pt = bid / 80; }
  else { int b = bid - 160; dir = 1; h = b % 5; n = (b / 5) % 16; pt = b / 80; }
  int Lq = dir ? 200 : 100;
  int Lk = dir ? 100 : 200;
  int Lk4 = Lk >> 2;
  int K4STR = dir ? 27 : 51;
  const int* kids = dir ? doc_vec : body_vec + n * BODY_LL;
  __shared__ float4 Kt4[60 * 51];
  __shared__ float red[4][64];
  float* Ktf = (float*)Kt4;
  int RS = K4STR * 4;
  for (int idx = threadIdx.x; idx < Lk * 15; idx += 256) {
    int r = idx / 15, c = idx - r * 15;
    float4 v = *(const float4*)(embed + (size_t)kids[r] * DDIM + h * HDIM + c * 4);
    Ktf[(c * 4 + 0) * RS + r] = v.x;
    Ktf[(c * 4 + 1) * RS + r] = v.y;
    Ktf[(c * 4 + 2) * RS + r] = v.z;
    Ktf[(c * 4 + 3) * RS + r] = v.w;
  }
  __syncthreads();
  int lane = threadIdx.x & 63;
  int w = __builtin_amdgcn_readfirstlane(threadIdx.x >> 6);
  int dl = (lane < HDIM) ? lane : (HDIM - 1);
  const float4* Krow = Kt4 + dl * K4STR;
  const float* Pb = P + (size_t)((n * 2 + dir) * NHEADS + h) * 20000;
  float omax = -1e30f;
#pragma unroll
  for (int p = 0; p < 4; p++) {
    int q0 = pt * 64 + p * 16 + w * 4;
    int qa0 = min(q0, Lq - 1), qa1 = min(q0 + 1, Lq - 1);
    int qa2 = min(q0 + 2, Lq - 1), qa3 = min(q0 + 3, Lq - 1);
    const float4* P0 = (const float4*)(Pb + (size_t)qa0 * Lk);
    const float4* P1 = (const float4*)(Pb + (size_t)qa1 * Lk);
    const float4* P2 = (const float4*)(Pb + (size_t)qa2 * Lk);
    const float4* P3 = (const float4*)(Pb + (size_t)qa3 * Lk);
    float o0 = 0.f, o1 = 0.f, o2 = 0.f, o3 = 0.f;
    for (int k4 = 0; k4 < Lk4; k4++) {
      float4 pp0 = P0[k4], pp1 = P1[k4], pp2 = P2[k4], pp3 = P3[k4];
      float4 kk = Krow[k4];
      o0 += pp0.x * kk.x + pp0.y * kk.y + pp0.z * kk.z + pp0.w * kk.w;
      o1 += pp1.x * kk.x + pp1.y * kk.y + pp1.z * kk.z + pp1.w * kk.w;
      o2 += pp2.x * kk.x + pp2.y * kk.y + pp2.z * kk.z + pp2.w * kk.w;
      o3 += pp3.x * kk.x + pp3.y * kk.y + pp3.z * kk.z + pp3.w * kk.w;
    }
    if (q0 < Lq)     omax = fmaxf(omax, o0);
    if (q0 + 1 < Lq) omax = fmaxf(omax, o1);
    if (q0 + 2 < Lq) omax = fmaxf(omax, o2);
    if (q0 + 3 < Lq) omax = fmaxf(omax, o3);
  }
  red[threadIdx.x >> 6][lane] = omax;
  __syncthreads();
  if (threadIdx.x < 64 && lane < HDIM) {
    float m4 = fmaxf(fmaxf(red[0][lane], red[1][lane]),
                     fmaxf(red[2][lane], red[3][lane]));
    float* dst = dir ? pv1 + (size_t)((n * NHEADS + h) * 4 + pt) * HDIM
                     : pv0 + (size_t)((n * NHEADS + h) * 2 + pt) * HDIM;
    dst[lane] = m4;
  }
}

// ---------------------------------------------------------------------------
__global__ __launch_bounds__(256) void mlp_kernel(
    const float* __restrict__ pv0, const float* __restrict__ pv1,
    const float* __restrict__ w1, const float* __restrict__ b1,
    const float* __restrict__ w2, const float* __restrict__ b2,
    float* __restrict__ att_score) {
  int n = blockIdx.x, tid = threadIdx.x;
  __shared__ float comb[600];
  for (int idx = tid; idx < 300; idx += 256) {
    int h = idx / 60, d = idx - h * 60;
    float mx = -1e30f;
#pragma unroll
    for (int pt = 0; pt < 2; pt++)
      mx = fmaxf(mx, pv0[(size_t)((n * NHEADS + h) * 2 + pt) * HDIM + d]);
    comb[idx] = mx;
    mx = -1e30f;
#pragma unroll
    for (int pt = 0; pt < 4; pt++)
      mx = fmaxf(mx, pv1[(size_t)((n * NHEADS + h) * 4 + pt) * HDIM + d]);
    comb[300 + idx] = mx;
  }
  __syncthreads();
  float partial = 0.f;
  for (int j = tid; j < 300; j += 256) {
    float hh = b1[j];
    for (int k = 0; k < 600; k++) hh += comb[k] * w1[k * 300 + j];
    partial += fmaxf(hh, 0.f) * w2[j];
  }
  __shared__ float redd[256];
  redd[tid] = partial;
  __syncthreads();
  for (int s = 128; s > 0; s >>= 1) {
    if (tid < s) redd[tid] += redd[tid + s];
    __syncthreads();
  }
  if (tid == 0) att_score[n] = 1.0f / (1.0f + expf(-(redd[0] + b2[0])));
}

// ---------------------------------------------------------------------------
__global__ __launch_bounds__(256) void final_kernel(
    const float* __restrict__ ms,
    const float* __restrict__ mc,
    const float* __restrict__ title,
    const float* __restrict__ bert,
    const float* __restrict__ att_score,
    const float* __restrict__ m2c_prior,
    const float* __restrict__ hand,
    const float* __restrict__ local_att,
    const float* __restrict__ w7,
    const float* __restrict__ b7,
    float* __restrict__ out) {
  int m = blockIdx.x, tid = threadIdx.x;
  __shared__ float sms[FNUM], smc[FNUM], smd[FNUM];
  __shared__ float snorm[3], sscore[16], wred[3][4];
  for (int i = tid; i < FNUM; i += 256) {
    sms[i] = ms[m * FNUM + i];
    smc[i] = mc[m * FNUM + i];
    smd[i] = bert[i];
  }
  __syncthreads();
  float p1 = 0.f, p2 = 0.f, p3 = 0.f;
  for (int i = tid; i < FNUM; i += 256) {
    float a = sms[i], b = smc[i], c = smd[i];
    p1 += a * a; p2 += b * b; p3 += c * c;
  }
#pragma unroll
  for (int o = 32; o >= 1; o >>= 1) {
    p1 += __shfl_xor(p1, o); p2 += __shfl_xor(p2, o); p3 += __shfl_xor(p3, o);
  }
  int wid = tid >> 6, lane = tid & 63;
  if (lane == 0) { wred[0][wid] = p1; wred[1][wid] = p2; wred[2][wid] = p3; }
  __syncthreads();
  if (tid == 0) {
    snorm[0] = fmaxf(sqrtf(wred[0][0] + wred[0][1] + wred[0][2] + wred[0][3]), 1e-6f);
    snorm[1] = fmaxf(sqrtf(wred[1][0] + wred[1][1] + wred[1][2] + wred[1][3]), 1e-6f);
    snorm[2] = fmaxf(sqrtf(wred[2][0] + wred[2][1] + wred[2][2] + wred[2][3]), 1e-6f);
  }
  __syncthreads();
  int nI = tid >> 4, j = tid & 15;
  float d1 = 0.f, d2 = 0.f, d3 = 0.f, d4 = 0.f;
  for (int i = j; i < FNUM; i += 16) {
    float t = title[nI * FNUM + i];
    d1 += sms[i] * t; d2 += smc[i] * t; d3 += smd[i] * t; d4 += t * t;
  }
#pragma unroll
  for (int o = 8; o >= 1; o >>= 1) {
    d1 += __shfl_xor(d1, o); d2 += __shfl_xor(d2, o);
    d3 += __shfl_xor(d3, o); d4 += __shfl_xor(d4, o);
  }
  if (j == 0) {
    float nt = fmaxf(sqrtf(d4), 1e-6f);
    float cos_st = d1 / (snorm[0] * nt);
    float cos_ct = d2 / (snorm[1] * nt);
    float cos_dt = d3 / (snorm[2] * nt);
    float score = hand[nI] * w7[0] + m2c_prior[nI] * w7[1] +
                  local_att[m * NN + nI] * w7[2] + att_score[nI] * w7[3] +
                  cos_st * w7[4] + cos_dt * w7[5] + cos_ct * w7[6] + b7[0];
    sscore[nI] = score;
  }
  __syncthreads();
  if (tid < 16) {
    float x = sscore[tid];
    float s = x;
#pragma unroll
    for (int o = 8; o >= 1; o >>= 1) s += __shfl_xor(s, o);
    float mu = s * (1.0f / 16.0f);
    float dv = (x - mu) * (x - mu);
    float vs = dv;
#pragma unroll
    for (int o = 8; o >= 1; o >>= 1) vs += __shfl_xor(vs, o);
    float sd = sqrtf(vs * (1.0f / 15.0f));
    float z = (x - mu) / sd;
    float zm = z;
#pragma unroll
    for (int o = 8; o >= 1; o >>= 1) zm = fmaxf(zm, __shfl_xor(zm, o));
    float e = expf(z - zm);
    float es = e;
#pragma unroll
    for (int o = 8; o >= 1; o >>= 1) es += __shfl_xor(es, o);
    float sm = e / es;
    float zmin = z;
#pragma unroll
    for (int o = 8; o >= 1; o >>= 1) zmin = fminf(zmin, __shfl_xor(zmin, o));
    float u0 = (z + 1.0f - zmin) / (zm - zmin);
    float us = u0;
#pragma unroll
    for (int o = 8; o >= 1; o >>= 1) us += __shfl_xor(us, o);
    float u = u0 / us;
    out[m * NN + tid] = z;
    out[MM * NN + m * NN + tid] = sm;
    out[2 * MM * NN + m * NN + tid] = u;
  }
}

// ---------------------------------------------------------------------------
extern "C" void kernel_launch(void* const* d_in, const int* in_sizes, int n_in,
                              void* d_out, int out_size, void* d_ws, size_t ws_size,
                              hipStream_t stream) {
  const int*   mention_vec   = (const int*)d_in[3];
  const int*   context_vec   = (const int*)d_in[4];
  const int*   doc_vec       = (const int*)d_in[5];
  const float* title_vec     = (const float*)d_in[6];
  const int*   body_vec      = (const int*)d_in[7];
  const float* m2c_prior     = (const float*)d_in[9];
  const int*   men2cands     = (const int*)d_in[10];
  const int*   contexts_ids  = (const int*)d_in[11];
  const float* hand_features = (const float*)d_in[12];
  const float* bert_doc_vec  = (const float*)d_in[13];
  const float* embed_table   = (const float*)d_in[14];
  const float* conv_ms_w     = (const float*)d_in[15];
  const float* conv_ms_b     = (const float*)d_in[16];
  const float* conv_mc_w     = (const float*)d_in[17];
  const float* conv_mc_b     = (const float*)d_in[18];
  const float* layer_local_w = (const float*)d_in[19];
  const float* layer_local_b = (const float*)d_in[20];
  const float* att_w1        = (const float*)d_in[21];
  const float* att_b1        = (const float*)d_in[22];
  const float* att_w2        = (const float*)d_in[23];
  const float* att_b2        = (const float*)d_in[24];

  float* ws     = (float*)d_ws;
  float* msg    = ws + OFF_MSG;
  float* ctx2g  = ws + OFF_CTX2G;
  float* candg  = ws + OFF_CANDG;
  float* ms     = ws + OFF_MS;
  float* mc     = ws + OFF_MC;
  float* pv0    = ws + OFF_PV0;
  float* pv1    = ws + OFF_PV1;
  float* att_sc = ws + OFF_ASC;
  float* latt   = ws + OFF_LATT;
  u16*   Abf    = (u16*)(ws + OFF_ABF);
  u16*   WTmc   = (u16*)(ws + OFF_WTMC);
  float* WTms   = ws + OFF_WTMS;
  float* P      = ws + OFF_P;
  float* out    = (float*)d_out;

  mega_prep_kernel<<<dim3(18378), dim3(256), 0, stream>>>(
      embed_table, mention_vec, context_vec, contexts_ids, men2cands,
      conv_mc_w, conv_ms_w, ws, mc, (u32*)Abf, (u32*)WTmc, WTms);
  conv_gemm_kernel<<<dim3(GN / 64, GM / 64), dim3(256), 0, stream>>>(
      Abf, WTmc, conv_mc_b, mc);
  mega_mid_kernel<<<dim3(1136), dim3(256), 0, stream>>>(
      embed_table, doc_vec, body_vec, msg, WTms, conv_ms_b, candg, ctx2g,
      ms, P, latt);
  attn_pv_kernel<<<dim3(480), dim3(256), 0, stream>>>(
      embed_table, doc_vec, body_vec, P, pv0, pv1);
  mlp_kernel<<<dim3(NN), dim3(256), 0, stream>>>(pv0, pv1, att_w1, att_b1, att_w2, att_b2, att_sc);
  final_kernel<<<dim3(MM), dim3(256), 0, stream>>>(
      ms, mc, title_vec, bert_doc_vec, att_sc, m2c_prior, hand_features,
      latt, layer_local_w, layer_local_b, out);
}

// Round 9
// 436.703 us; speedup vs baseline: 1.0035x; 1.0035x over previous
//
#include <hip/hip_runtime.h>

#define MM 64
#define NN 16
#define DDIM 300
#define FNUM 768
#define SURF_LL 4
#define CTX_LL 50
#define DOC_LL 100
#define BODY_LL 200
#define NHEADS 5
#define HDIM 60

// GEMM dims for conv_mc:  C[GM][GN] = A[GM][GK] * B^T, K padded 1500->1536
#define GM 2944   // 64 m * 46 t
#define GK 1536
#define GN 768

typedef unsigned short u16;
typedef unsigned int u32;
typedef __attribute__((ext_vector_type(8))) short short8;
typedef __attribute__((ext_vector_type(4))) float f32x4;

// ---- workspace layout (float offsets) ----
#define OFF_MSG    0                    // mention emb [256][300]
#define OFF_CTX2G  76800                // contexts_ids emb [3200][300]
#define OFF_CANDG  1036800              // men2cands emb [1024][300]
#define OFF_MS     1344000              // ms [64][768]
#define OFF_MC     1393152              // mc [64][768] (atomic mean accum)
#define OFF_PV0    1442304              // [16][5][2][60]
#define OFF_PV1    1451904              // [16][5][4][60]
#define OFF_ASC    1471104              // [16]
#define OFF_LATT   1471120              // [64][16]
#define OFF_ABF    1472144              // u16[GM*GK]
#define OFF_WTMC   (OFF_ABF + GM*GK/2)  // u16[GN*GK]
#define OFF_WTMS   (OFF_WTMC + GN*GK/2) // float[600*768]
#define OFF_P      (OFF_WTMS + 600*768) // attn P [160][20000]

__device__ __forceinline__ u16 f2bf(float x) {
  union { float f; u32 u; } v; v.f = x;
  u32 r = v.u + 0x7FFFu + ((v.u >> 16) & 1u);
  return (u16)(r >> 16);
}

// ---------------------------------------------------------------------------
// MEGA-PREP: gather embeddings + zero mc + im2col bf16 + weight repacks.
__global__ __launch_bounds__(256) void mega_prep_kernel(
    const float* __restrict__ embed,
    const int* __restrict__ mention_vec,
    const int* __restrict__ context_vec,
    const int* __restrict__ contexts_ids,
    const int* __restrict__ men2cands,
    const float* __restrict__ Wmc,
    const float* __restrict__ Wms,
    float* __restrict__ dst, float* __restrict__ mc,
    u32* __restrict__ Abf, u32* __restrict__ WTmc, float* __restrict__ WTms) {
  int bid = blockIdx.x;
  if (bid < 5250) {
    int e = bid * 256 + threadIdx.x;
    int row = e / DDIM;
    int col = e - row * DDIM;
    int tok;
    if (row < 256)       tok = mention_vec[row];
    else if (row < 3456) tok = contexts_ids[row - 256];
    else                 tok = men2cands[row - 3456];
    dst[e] = embed[(size_t)tok * DDIM + col];
  } else if (bid < 5442) {
    mc[(bid - 5250) * 256 + threadIdx.x] = 0.f;
  } else if (bid < 14274) {
    int idx = (bid - 5442) * 256 + threadIdx.x;  // one u32 = 2 bf16
    int r = idx / (GK / 2);
    int kp = idx - r * (GK / 2);
    int k = kp * 2;
    int m = r / 46, t = r - m * 46;
    u32 out = 0;
#pragma unroll
    for (int j = 0; j < 2; j++) {
      int kj = k + j;
      u16 h = 0;
      if (kj < 1500) {
        int tap = kj / 300;
        int d = kj - tap * 300;
        int tok = context_vec[m * CTX_LL + t + tap];
        h = f2bf(embed[(size_t)tok * DDIM + d]);
      }
      out |= (u32)h << (16 * j);
    }
    Abf[idx] = out;
  } else if (bid < 16578) {
    int idx = (bid - 14274) * 256 + threadIdx.x;
    int n = idx / (GK / 2);
    int kp = idx - n * (GK / 2);
    int k = kp * 2;
    u32 out = 0;
#pragma unroll
    for (int j = 0; j < 2; j++) {
      int kj = k + j;
      u16 h = 0;
      if (kj < 1500) {
        int tap = kj / 300;
        int d = kj - tap * 300;
        h = f2bf(Wmc[(size_t)n * 1500 + d * 5 + tap]);
      }
      out |= (u32)h << (16 * j);
    }
    WTmc[idx] = out;
  } else {
    int idx = (bid - 16578) * 256 + threadIdx.x;  // 600*768
    int k = idx / FNUM;
    int f = idx - k * FNUM;
    WTms[idx] = Wms[(size_t)f * 600 + k];
  }
}

// ---------------------------------------------------------------------------
// bf16 MFMA GEMM with fused relu+mean epilogue (atomicAdd into mc).
__global__ __launch_bounds__(256) void conv_gemm_kernel(
    const u16* __restrict__ A,    // [GM][GK] bf16
    const u16* __restrict__ B,    // [GN][GK] bf16 (n-major)
    const float* __restrict__ bias,
    float* __restrict__ mc) {     // [64][768]
  int bn = blockIdx.x, bm = blockIdx.y;
  __shared__ u16 As[64][72];
  __shared__ u16 Bs[64][72];
  int tid = threadIdx.x;
  int w = tid >> 6, lane = tid & 63;
  int wr = w >> 1, wc = w & 1;
  int lg = lane >> 4, lm = lane & 15;
  f32x4 acc[2][2];
#pragma unroll
  for (int i = 0; i < 2; i++)
#pragma unroll
    for (int j = 0; j < 2; j++) acc[i][j] = (f32x4)0.f;
  int c0row = tid >> 3, ck = (tid & 7) * 8;
  const u16* Ag = A + (size_t)(bm * 64) * GK;
  const u16* Bg = B + (size_t)(bn * 64) * GK;
  for (int kt = 0; kt < GK / 64; kt++) {
    int k0 = kt * 64;
    uint4 av0 = *(const uint4*)(Ag + (size_t)c0row * GK + k0 + ck);
    uint4 av1 = *(const uint4*)(Ag + (size_t)(c0row + 32) * GK + k0 + ck);
    uint4 bv0 = *(const uint4*)(Bg + (size_t)c0row * GK + k0 + ck);
    uint4 bv1 = *(const uint4*)(Bg + (size_t)(c0row + 32) * GK + k0 + ck);
    __syncthreads();
    *(uint4*)&As[c0row][ck] = av0;
    *(uint4*)&As[c0row + 32][ck] = av1;
    *(uint4*)&Bs[c0row][ck] = bv0;
    *(uint4*)&Bs[c0row + 32][ck] = bv1;
    __syncthreads();
#pragma unroll
    for (int kk = 0; kk < 2; kk++) {
      short8 af0 = *(const short8*)&As[wr * 32 + lm][kk * 32 + lg * 8];
      short8 af1 = *(const short8*)&As[wr * 32 + 16 + lm][kk * 32 + lg * 8];
      short8 bf0 = *(const short8*)&Bs[wc * 32 + lm][kk * 32 + lg * 8];
      short8 bf1 = *(const short8*)&Bs[wc * 32 + 16 + lm][kk * 32 + lg * 8];
      acc[0][0] = __builtin_amdgcn_mfma_f32_16x16x32_bf16(af0, bf0, acc[0][0], 0, 0, 0);
      acc[0][1] = __builtin_amdgcn_mfma_f32_16x16x32_bf16(af0, bf1, acc[0][1], 0, 0, 0);
      acc[1][0] = __builtin_amdgcn_mfma_f32_16x16x32_bf16(af1, bf0, acc[1][0], 0, 0, 0);
      acc[1][1] = __builtin_amdgcn_mfma_f32_16x16x32_bf16(af1, bf1, acc[1][1], 0, 0, 0);
    }
  }
#pragma unroll
  for (int mf = 0; mf < 2; mf++)
#pragma unroll
    for (int nf = 0; nf < 2; nf++) {
      int col = bn * 64 + wc * 32 + nf * 16 + lm;
      float bb = bias[col];
      int base = bm * 64 + wr * 32 + mf * 16 + lg * 4;
      int mcur = base / 46;
      float s = 0.f;
#pragma unroll
      for (int r = 0; r < 4; r++) {
        float v = fmaxf(acc[mf][nf][r] + bb, 0.f) * (1.0f / 46.0f);
        int mm = (base + r) / 46;
        if (mm != mcur) { atomicAdd(&mc[mcur * FNUM + col], s); s = 0.f; mcur = mm; }
        s += v;
      }
      atomicAdd(&mc[mcur * FNUM + col], s);
    }
}

// ---------------------------------------------------------------------------
// Fused QK^T + softmax with transposed K layout: Kt4[c][k] holds d=c*4..c*4+3
// of K row k as one float4.  Inner loop: consecutive lanes read consecutive
// float4s (conflict-free ds_read_b128); Q rows broadcast b128.  c-loop pinned
// unroll(1) -> VGPR-lean (R6's blowup was the full unroll).
template <int DIR>
__device__ __forceinline__ void scores_body(
    const float* __restrict__ embed, const int* __restrict__ doc_vec,
    const int* __restrict__ body_vec, float* __restrict__ P, int b,
    float* __restrict__ smem) {
  constexpr int Lq = DIR ? 200 : 100;
  constexpr int Lk = DIR ? 100 : 200;
  constexpr int KPL = DIR ? 2 : 4;
  int qt = b / 80;
  int rem = b - qt * 80;
  int n = rem / 5, h = rem - n * 5;
  const int* qids = DIR ? body_vec + n * BODY_LL : doc_vec;
  const int* kids = DIR ? doc_vec : body_vec + n * BODY_LL;
  float4* Kt4 = (float4*)smem;     // [15][Lk]
  float* Qs = smem + 48000 / 4;    // [32][64] at float offset 12000
  for (int idx = threadIdx.x; idx < 15 * Lk; idx += 256) {
    int c = idx / Lk, r = idx - c * Lk;  // consecutive lanes -> consecutive r
    Kt4[idx] = *(const float4*)(embed + (size_t)kids[r] * DDIM + h * HDIM + c * 4);
  }
  for (int idx = threadIdx.x; idx < 32 * 15; idx += 256) {
    int r = idx / 15, c = idx - r * 15;
    int q = qt * 32 + r; if (q >= Lq) q = Lq - 1;
    *(float4*)&Qs[r * 64 + c * 4] =
        *(const float4*)(embed + (size_t)qids[q] * DDIM + h * HDIM + c * 4);
  }
  __syncthreads();
  int w = threadIdx.x >> 6, lane = threadIdx.x & 63;
  int kc[KPL];
  bool kval[KPL];
#pragma unroll
  for (int j = 0; j < KPL; j++) {
    int kk = j * 64 + lane;
    kval[j] = (kk < Lk);
    kc[j] = kval[j] ? kk : (Lk - 1);
  }
  float acc[8][KPL];
#pragma unroll
  for (int i = 0; i < 8; i++)
#pragma unroll
    for (int j = 0; j < KPL; j++) acc[i][j] = 0.f;
#pragma unroll 1
  for (int c = 0; c < 15; c++) {
    float4 kv[KPL];
#pragma unroll
    for (int j = 0; j < KPL; j++) kv[j] = Kt4[c * Lk + kc[j]];
#pragma unroll
    for (int i = 0; i < 8; i++) {
      float4 q4 = *(const float4*)&Qs[(w * 8 + i) * 64 + c * 4];
#pragma unroll
      for (int j = 0; j < KPL; j++)
        acc[i][j] += q4.x * kv[j].x + q4.y * kv[j].y +
                     q4.z * kv[j].z + q4.w * kv[j].w;
    }
  }
  const float scale = 0.12909944487358056f;  // 1/sqrt(60)
#pragma unroll
  for (int i = 0; i < 8; i++) {
    int q = qt * 32 + w * 8 + i;
    float mx = -1e30f;
#pragma unroll
    for (int j = 0; j < KPL; j++)
      if (kval[j]) mx = fmaxf(mx, acc[i][j]);
#pragma unroll
    for (int o = 32; o >= 1; o >>= 1) mx = fmaxf(mx, __shfl_xor(mx, o));
    float mxs = mx * scale;
    float pe[KPL];
    float s = 0.f;
#pragma unroll
    for (int j = 0; j < KPL; j++) {
      pe[j] = kval[j] ? __expf(acc[i][j] * scale - mxs) : 0.f;
      s += pe[j];
    }
#pragma unroll
    for (int o = 32; o >= 1; o >>= 1) s += __shfl_xor(s, o);
    float inv = 1.0f / s;
    if (q < Lq) {
      float* rowp = P + (size_t)((n * 2 + DIR) * NHEADS + h) * 20000 + q * Lk;
#pragma unroll
      for (int j = 0; j < KPL; j++)
        if (kval[j]) rowp[j * 64 + lane] = pe[j] * inv;
    }
  }
}

// ---------------------------------------------------------------------------
// conv_ms body (no LDS).
__device__ __forceinline__ void conv_ms_body(
    const float* __restrict__ msg, const float* __restrict__ WT,
    const float* __restrict__ B, float* __restrict__ ms, int b) {
  int m = b / 3, fi = b - m * 3;
  int f = fi * 256 + threadIdx.x;
  const float* x = msg + m * SURF_LL * DDIM;
  float a0 = 0.f, a1 = 0.f, a2 = 0.f;
  for (int d = 0; d < DDIM; d++) {
    float v0 = x[d], v1 = x[DDIM + d], v2 = x[2 * DDIM + d], v3 = x[3 * DDIM + d];
    float wA = WT[(size_t)(2 * d) * FNUM + f];
    float wB = WT[(size_t)(2 * d + 1) * FNUM + f];
    a0 += v0 * wA + v1 * wB;
    a1 += v1 * wA + v2 * wB;
    a2 += v2 * wA + v3 * wB;
  }
  float bb = B[f];
  float r = fmaxf(a0 + bb, 0.f) + fmaxf(a1 + bb, 0.f) + fmaxf(a2 + bb, 0.f);
  ms[m * FNUM + f] = r * (1.0f / 3.0f);
}

// tok + ctxv fused (cand via 16-lane-broadcast global reads; ctx tile in LDS).
__device__ __forceinline__ void tokctxv_body(
    const float* __restrict__ candg, const float* __restrict__ ctx2g,
    float* __restrict__ local_att, int m, float* __restrict__ smem) {
  float* ctx   = smem;          // [16][300]
  float* tokb  = smem + 4800;   // [16][17]
  float* tkmx  = smem + 5072;   // [64] (50 used)
  float* pp    = smem + 5136;   // [64]
  float* sctxv = smem + 5200;   // [300]
  int tid = threadIdx.x;
  int nI = tid >> 4, tt = tid & 15;
  const float4* ca = (const float4*)(candg + (size_t)(m * NN + nI) * DDIM);
  for (int tile = 0; tile < 4; tile++) {
    int cbase = tile * 16;
    __syncthreads();
    for (int i = tid; i < 16 * DDIM; i += 256) {
      int rr = i / DDIM, cc = i - rr * DDIM;
      int t = cbase + rr;
      ctx[rr * DDIM + cc] = (t < CTX_LL) ? ctx2g[(size_t)(m * CTX_LL + t) * DDIM + cc] : 0.f;
    }
    __syncthreads();
    const float4* cb = (const float4*)(ctx + tt * DDIM);
    float dsum = 0.f;
#pragma unroll
    for (int c = 0; c < 75; c++) {
      float4 a = ca[c], b = cb[c];
      dsum += a.x * b.x + a.y * b.y + a.z * b.z + a.w * b.w;
    }
    tokb[nI * 17 + tt] = dsum;
    __syncthreads();
    if (tid < 16) {
      float mx = -1e30f;
      for (int nn = 0; nn < NN; nn++) mx = fmaxf(mx, tokb[nn * 17 + tid]);
      int t = cbase + tid;
      if (t < CTX_LL) tkmx[t] = mx;
    }
  }
  __syncthreads();
  if (tid < 64) {
    float v = (tid < CTX_LL) ? tkmx[tid] : -1e30f;
    float mx = v;
#pragma unroll
    for (int o = 32; o >= 1; o >>= 1) mx = fmaxf(mx, __shfl_xor(mx, o));
    float e = (tid < CTX_LL) ? expf(v - mx) : 0.f;
    float s = e;
#pragma unroll
    for (int o = 32; o >= 1; o >>= 1) s += __shfl_xor(s, o);
    pp[tid] = e / s;
  }
  __syncthreads();
  for (int d = tid; d < DDIM; d += 256) {
    float acc = 0.f;
    for (int t = 0; t < CTX_LL; t++)
      acc += pp[t] * ctx2g[(size_t)(m * CTX_LL + t) * DDIM + d];
    sctxv[d] = acc;
  }
  __syncthreads();
  int j = tid & 15;
  const float* crow = candg + (size_t)(m * NN + nI) * DDIM;
  float dd = 0.f;
  for (int i = j; i < DDIM; i += 16) dd += crow[i] * sctxv[i];
#pragma unroll
  for (int o = 8; o >= 1; o >>= 1) dd += __shfl_xor(dd, o);
  if (j == 0) local_att[m * NN + nI] = dd;
}

// MEGA-MID: [0,64) tok+ctxv ; [64,384) scores dir0 ; [384,944) scores dir1 ;
// [944,1136) conv_ms.  smem 14048 floats = 56.2 KB -> 2 blocks/CU
// (proven sufficient in R5; limiter is LDS instr count, now 4x lower).
__global__ __launch_bounds__(256) void mega_mid_kernel(
    const float* __restrict__ embed,
    const int* __restrict__ doc_vec,
    const int* __restrict__ body_vec,
    const float* __restrict__ msg,
    const float* __restrict__ WTms,
    const float* __restrict__ Bms,
    const float* __restrict__ candg,
    const float* __restrict__ ctx2g,
    float* __restrict__ ms,
    float* __restrict__ P,
    float* __restrict__ local_att) {
  __shared__ __align__(16) float smem[14048];
  int bid = blockIdx.x;
  if (bid < 64) {
    tokctxv_body(candg, ctx2g, local_att, bid, smem);
  } else if (bid < 384) {
    scores_body<0>(embed, doc_vec, body_vec, P, bid - 64, smem);
  } else if (bid < 944) {
    scores_body<1>(embed, doc_vec, body_vec, P, bid - 384, smem);
  } else {
    conv_ms_body(msg, WTms, Bms, ms, bid - 944);
  }
}

// ---------------------------------------------------------------------------
// PV + max-pool over q, both dirs merged (unchanged since R4).
__global__ __launch_bounds__(256) void attn_pv_kernel(
    const float* __restrict__ embed,
    const int* __restrict__ doc_vec,
    const int* __restrict__ body_vec,
    const float* __restrict__ P,
    float* __restrict__ pv0,   // [16][5][2][60]
    float* __restrict__ pv1) { // [16][5][4][60]
  int bid = blockIdx.x;
  int dir, pt, n, h;
  if (bid < 160) { dir = 0; h = bid % 5; n = (bid / 5) % 16; pt = bid / 80; }
  else { int b = bid - 160; dir = 1; h = b % 5; n = (b / 5) % 16; pt = b / 80; }
  int Lq = dir ? 200 : 100;
  int Lk = dir ? 100 : 200;
  int Lk4 = Lk >> 2;
  int K4STR = dir ? 27 : 51;
  const int* kids = dir ? doc_vec : body_vec + n * BODY_LL;
  __shared__ float4 Kt4[60 * 51];
  __shared__ float red[4][64];
  float* Ktf = (float*)Kt4;
  int RS = K4STR * 4;
  for (int idx = threadIdx.x; idx < Lk * 15; idx += 256) {
    int r = idx / 15, c = idx - r * 15;
    float4 v = *(const float4*)(embed + (size_t)kids[r] * DDIM + h * HDIM + c * 4);
    Ktf[(c * 4 + 0) * RS + r] = v.x;
    Ktf[(c * 4 + 1) * RS + r] = v.y;
    Ktf[(c * 4 + 2) * RS + r] = v.z;
    Ktf[(c * 4 + 3) * RS + r] = v.w;
  }
  __syncthreads();
  int lane = threadIdx.x & 63;
  int w = __builtin_amdgcn_readfirstlane(threadIdx.x >> 6);
  int dl = (lane < HDIM) ? lane : (HDIM - 1);
  const float4* Krow = Kt4 + dl * K4STR;
  const float* Pb = P + (size_t)((n * 2 + dir) * NHEADS + h) * 20000;
  float omax = -1e30f;
#pragma unroll
  for (int p = 0; p < 4; p++) {
    int q0 = pt * 64 + p * 16 + w * 4;
    int qa0 = min(q0, Lq - 1), qa1 = min(q0 + 1, Lq - 1);
    int qa2 = min(q0 + 2, Lq - 1), qa3 = min(q0 + 3, Lq - 1);
    const float4* P0 = (const float4*)(Pb + (size_t)qa0 * Lk);
    const float4* P1 = (const float4*)(Pb + (size_t)qa1 * Lk);
    const float4* P2 = (const float4*)(Pb + (size_t)qa2 * Lk);
    const float4* P3 = (const float4*)(Pb + (size_t)qa3 * Lk);
    float o0 = 0.f, o1 = 0.f, o2 = 0.f, o3 = 0.f;
    for (int k4 = 0; k4 < Lk4; k4++) {
      float4 pp0 = P0[k4], pp1 = P1[k4], pp2 = P2[k4], pp3 = P3[k4];
      float4 kk = Krow[k4];
      o0 += pp0.x * kk.x + pp0.y * kk.y + pp0.z * kk.z + pp0.w * kk.w;
      o1 += pp1.x * kk.x + pp1.y * kk.y + pp1.z * kk.z + pp1.w * kk.w;
      o2 += pp2.x * kk.x + pp2.y * kk.y + pp2.z * kk.z + pp2.w * kk.w;
      o3 += pp3.x * kk.x + pp3.y * kk.y + pp3.z * kk.z + pp3.w * kk.w;
    }
    if (q0 < Lq)     omax = fmaxf(omax, o0);
    if (q0 + 1 < Lq) omax = fmaxf(omax, o1);
    if (q0 + 2 < Lq) omax = fmaxf(omax, o2);
    if (q0 + 3 < Lq) omax = fmaxf(omax, o3);
  }
  red[threadIdx.x >> 6][lane] = omax;
  __syncthreads();
  if (threadIdx.x < 64 && lane < HDIM) {
    float m4 = fmaxf(fmaxf(red[0][lane], red[1][lane]),
                     fmaxf(red[2][lane], red[3][lane]));
    float* dst = dir ? pv1 + (size_t)((n * NHEADS + h) * 4 + pt) * HDIM
                     : pv0 + (size_t)((n * NHEADS + h) * 2 + pt) * HDIM;
    dst[lane] = m4;
  }
}

// ---------------------------------------------------------------------------
__global__ __launch_bounds__(256) void mlp_kernel(
    const float* __restrict__ pv0, const float* __restrict__ pv1,
    const float* __restrict__ w1, const float* __restrict__ b1,
    const float* __restrict__ w2, const float* __restrict__ b2,
    float* __restrict__ att_score) {
  int n = blockIdx.x, tid = threadIdx.x;
  __shared__ float comb[600];
  for (int idx = tid; idx < 300; idx += 256) {
    int h = idx / 60, d = idx - h * 60;
    float mx = -1e30f;
#pragma unroll
    for (int pt = 0; pt < 2; pt++)
      mx = fmaxf(mx, pv0[(size_t)((n * NHEADS + h) * 2 + pt) * HDIM + d]);
    comb[idx] = mx;
    mx = -1e30f;
#pragma unroll
    for (int pt = 0; pt < 4; pt++)
      mx = fmaxf(mx, pv1[(size_t)((n * NHEADS + h) * 4 + pt) * HDIM + d]);
    comb[300 + idx] = mx;
  }
  __syncthreads();
  float partial = 0.f;
  for (int j = tid; j < 300; j += 256) {
    float hh = b1[j];
    for (int k = 0; k < 600; k++) hh += comb[k] * w1[k * 300 + j];
    partial += fmaxf(hh, 0.f) * w2[j];
  }
  __shared__ float redd[256];
  redd[tid] = partial;
  __syncthreads();
  for (int s = 128; s > 0; s >>= 1) {
    if (tid < s) redd[tid] += redd[tid + s];
    __syncthreads();
  }
  if (tid == 0) att_score[n] = 1.0f / (1.0f + expf(-(redd[0] + b2[0])));
}

// ---------------------------------------------------------------------------
__global__ __launch_bounds__(256) void final_kernel(
    const float* __restrict__ ms,
    const float* __restrict__ mc,
    const float* __restrict__ title,
    const float* __restrict__ bert,
    const float* __restrict__ att_score,
    const float* __restrict__ m2c_prior,
    const float* __restrict__ hand,
    const float* __restrict__ local_att,
    const float* __restrict__ w7,
    const float* __restrict__ b7,
    float* __restrict__ out) {
  int m = blockIdx.x, tid = threadIdx.x;
  __shared__ float sms[FNUM], smc[FNUM], smd[FNUM];
  __shared__ float snorm[3], sscore[16], wred[3][4];
  for (int i = tid; i < FNUM; i += 256) {
    sms[i] = ms[m * FNUM + i];
    smc[i] = mc[m * FNUM + i];
    smd[i] = bert[i];
  }
  __syncthreads();
  float p1 = 0.f, p2 = 0.f, p3 = 0.f;
  for (int i = tid; i < FNUM; i += 256) {
    float a = sms[i], b = smc[i], c = smd[i];
    p1 += a * a; p2 += b * b; p3 += c * c;
  }
#pragma unroll
  for (int o = 32; o >= 1; o >>= 1) {
    p1 += __shfl_xor(p1, o); p2 += __shfl_xor(p2, o); p3 += __shfl_xor(p3, o);
  }
  int wid = tid >> 6, lane = tid & 63;
  if (lane == 0) { wred[0][wid] = p1; wred[1][wid] = p2; wred[2][wid] = p3; }
  __syncthreads();
  if (tid == 0) {
    snorm[0] = fmaxf(sqrtf(wred[0][0] + wred[0][1] + wred[0][2] + wred[0][3]), 1e-6f);
    snorm[1] = fmaxf(sqrtf(wred[1][0] + wred[1][1] + wred[1][2] + wred[1][3]), 1e-6f);
    snorm[2] = fmaxf(sqrtf(wred[2][0] + wred[2][1] + wred[2][2] + wred[2][3]), 1e-6f);
  }
  __syncthreads();
  int nI = tid >> 4, j = tid & 15;
  float d1 = 0.f, d2 = 0.f, d3 = 0.f, d4 = 0.f;
  for (int i = j; i < FNUM; i += 16) {
    float t = title[nI * FNUM + i];
    d1 += sms[i] * t; d2 += smc[i] * t; d3 += smd[i] * t; d4 += t * t;
  }
#pragma unroll
  for (int o = 8; o >= 1; o >>= 1) {
    d1 += __shfl_xor(d1, o); d2 += __shfl_xor(d2, o);
    d3 += __shfl_xor(d3, o); d4 += __shfl_xor(d4, o);
  }
  if (j == 0) {
    float nt = fmaxf(sqrtf(d4), 1e-6f);
    float cos_st = d1 / (snorm[0] * nt);
    float cos_ct = d2 / (snorm[1] * nt);
    float cos_dt = d3 / (snorm[2] * nt);
    float score = hand[nI] * w7[0] + m2c_prior[nI] * w7[1] +
                  local_att[m * NN + nI] * w7[2] + att_score[nI] * w7[3] +
                  cos_st * w7[4] + cos_dt * w7[5] + cos_ct * w7[6] + b7[0];
    sscore[nI] = score;
  }
  __syncthreads();
  if (tid < 16) {
    float x = sscore[tid];
    float s = x;
#pragma unroll
    for (int o = 8; o >= 1; o >>= 1) s += __shfl_xor(s, o);
    float mu = s * (1.0f / 16.0f);
    float dv = (x - mu) * (x - mu);
    float vs = dv;
#pragma unroll
    for (int o = 8; o >= 1; o >>= 1) vs += __shfl_xor(vs, o);
    float sd = sqrtf(vs * (1.0f / 15.0f));
    float z = (x - mu) / sd;
    float zm = z;
#pragma unroll
    for (int o = 8; o >= 1; o >>= 1) zm = fmaxf(zm, __shfl_xor(zm, o));
    float e = expf(z - zm);
    float es = e;
#pragma unroll
    for (int o = 8; o >= 1; o >>= 1) es += __shfl_xor(es, o);
    float sm = e / es;
    float zmin = z;
#pragma unroll
    for (int o = 8; o >= 1; o >>= 1) zmin = fminf(zmin, __shfl_xor(zmin, o));
    float u0 = (z + 1.0f - zmin) / (zm - zmin);
    float us = u0;
#pragma unroll
    for (int o = 8; o >= 1; o >>= 1) us += __shfl_xor(us, o);
    float u = u0 / us;
    out[m * NN + tid] = z;
    out[MM * NN + m * NN + tid] = sm;
    out[2 * MM * NN + m * NN + tid] = u;
  }
}

// ---------------------------------------------------------------------------
extern "C" void kernel_launch(void* const* d_in, const int* in_sizes, int n_in,
                              void* d_out, int out_size, void* d_ws, size_t ws_size,
                              hipStream_t stream) {
  const int*   mention_vec   = (const int*)d_in[3];
  const int*   context_vec   = (const int*)d_in[4];
  const int*   doc_vec       = (const int*)d_in[5];
  const float* title_vec     = (const float*)d_in[6];
  const int*   body_vec      = (const int*)d_in[7];
  const float* m2c_prior     = (const float*)d_in[9];
  const int*   men2cands     = (const int*)d_in[10];
  const int*   contexts_ids  = (const int*)d_in[11];
  const float* hand_features = (const float*)d_in[12];
  const float* bert_doc_vec  = (const float*)d_in[13];
  const float* embed_table   = (const float*)d_in[14];
  const float* conv_ms_w     = (const float*)d_in[15];
  const float* conv_ms_b     = (const float*)d_in[16];
  const float* conv_mc_w     = (const float*)d_in[17];
  const float* conv_mc_b     = (const float*)d_in[18];
  const float* layer_local_w = (const float*)d_in[19];
  const float* layer_local_b = (const float*)d_in[20];
  const float* att_w1        = (const float*)d_in[21];
  const float* att_b1        = (const float*)d_in[22];
  const float* att_w2        = (const float*)d_in[23];
  const float* att_b2        = (const float*)d_in[24];

  float* ws     = (float*)d_ws;
  float* msg    = ws + OFF_MSG;
  float* ctx2g  = ws + OFF_CTX2G;
  float* candg  = ws + OFF_CANDG;
  float* ms     = ws + OFF_MS;
  float* mc     = ws + OFF_MC;
  float* pv0    = ws + OFF_PV0;
  float* pv1    = ws + OFF_PV1;
  float* att_sc = ws + OFF_ASC;
  float* latt   = ws + OFF_LATT;
  u16*   Abf    = (u16*)(ws + OFF_ABF);
  u16*   WTmc   = (u16*)(ws + OFF_WTMC);
  float* WTms   = ws + OFF_WTMS;
  float* P      = ws + OFF_P;
  float* out    = (float*)d_out;

  mega_prep_kernel<<<dim3(18378), dim3(256), 0, stream>>>(
      embed_table, mention_vec, context_vec, contexts_ids, men2cands,
      conv_mc_w, conv_ms_w, ws, mc, (u32*)Abf, (u32*)WTmc, WTms);
  conv_gemm_kernel<<<dim3(GN / 64, GM / 64), dim3(256), 0, stream>>>(
      Abf, WTmc, conv_mc_b, mc);
  mega_mid_kernel<<<dim3(1136), dim3(256), 0, stream>>>(
      embed_table, doc_vec, body_vec, msg, WTms, conv_ms_b, candg, ctx2g,
      ms, P, latt);
  attn_pv_kernel<<<dim3(480), dim3(256), 0, stream>>>(
      embed_table, doc_vec, body_vec, P, pv0, pv1);
  mlp_kernel<<<dim3(NN), dim3(256), 0, stream>>>(pv0, pv1, att_w1, att_b1, att_w2, att_b2, att_sc);
  final_kernel<<<dim3(MM), dim3(256), 0, stream>>>(
      ms, mc, title_vec, bert_doc_vec, att_sc, m2c_prior, hand_features,
      latt, layer_local_w, layer_local_b, out);
}

// Round 10
// 416.267 us; speedup vs baseline: 1.0527x; 1.0491x over previous
//
#include <hip/hip_runtime.h>

#define MM 64
#define NN 16
#define DDIM 300
#define FNUM 768
#define SURF_LL 4
#define CTX_LL 50
#define DOC_LL 100
#define BODY_LL 200
#define NHEADS 5
#define HDIM 60

// GEMM dims for conv_mc:  C[GM][GN] = A[GM][GK] * B^T, K padded 1500->1536
#define GM 2944   // 64 m * 46 t
#define GK 1536
#define GN 768

typedef unsigned short u16;
typedef unsigned int u32;
typedef __attribute__((ext_vector_type(8))) short short8;
typedef __attribute__((ext_vector_type(4))) float f32x4;

// ---- workspace layout (float offsets) ----
#define OFF_MSG    0                    // mention emb [256][300]
#define OFF_CTX2G  76800                // contexts_ids emb [3200][300]
#define OFF_CANDG  1036800              // men2cands emb [1024][300]
#define OFF_MS     1344000              // ms [64][768]
#define OFF_MC     1393152              // mc [64][768] (atomic mean accum)
#define OFF_PV0    1442304              // [16][5][2][60]
#define OFF_PV1    1451904              // [16][5][4][60]
#define OFF_ASC    1471104              // [16]
#define OFF_LATT   1471120              // [64][16]
#define OFF_ABF    1472144              // u16[GM*GK]
#define OFF_WTMC   (OFF_ABF + GM*GK/2)  // u16[GN*GK]
#define OFF_WTMS   (OFF_WTMC + GN*GK/2) // float[600*768]
#define OFF_P      (OFF_WTMS + 600*768) // attn P [160][20000]

__device__ __forceinline__ u16 f2bf(float x) {
  union { float f; u32 u; } v; v.f = x;
  u32 r = v.u + 0x7FFFu + ((v.u >> 16) & 1u);
  return (u16)(r >> 16);
}

// ---------------------------------------------------------------------------
// MEGA-PREP: gather embeddings + zero mc + im2col bf16 + weight repacks.
// blocks: [0,5250) gather ; [5250,5442) mc zero ; [5442,14274) abuild ;
//         [14274,16578) wtmc ; [16578,18378) wtms
__global__ __launch_bounds__(256) void mega_prep_kernel(
    const float* __restrict__ embed,
    const int* __restrict__ mention_vec,
    const int* __restrict__ context_vec,
    const int* __restrict__ contexts_ids,
    const int* __restrict__ men2cands,
    const float* __restrict__ Wmc,
    const float* __restrict__ Wms,
    float* __restrict__ dst, float* __restrict__ mc,
    u32* __restrict__ Abf, u32* __restrict__ WTmc, float* __restrict__ WTms) {
  int bid = blockIdx.x;
  if (bid < 5250) {
    int e = bid * 256 + threadIdx.x;
    int row = e / DDIM;
    int col = e - row * DDIM;
    int tok;
    if (row < 256)       tok = mention_vec[row];
    else if (row < 3456) tok = contexts_ids[row - 256];
    else                 tok = men2cands[row - 3456];
    dst[e] = embed[(size_t)tok * DDIM + col];
  } else if (bid < 5442) {
    mc[(bid - 5250) * 256 + threadIdx.x] = 0.f;
  } else if (bid < 14274) {
    int idx = (bid - 5442) * 256 + threadIdx.x;  // one u32 = 2 bf16
    int r = idx / (GK / 2);
    int kp = idx - r * (GK / 2);
    int k = kp * 2;
    int m = r / 46, t = r - m * 46;
    u32 out = 0;
#pragma unroll
    for (int j = 0; j < 2; j++) {
      int kj = k + j;
      u16 h = 0;
      if (kj < 1500) {
        int tap = kj / 300;
        int d = kj - tap * 300;
        int tok = context_vec[m * CTX_LL + t + tap];
        h = f2bf(embed[(size_t)tok * DDIM + d]);
      }
      out |= (u32)h << (16 * j);
    }
    Abf[idx] = out;
  } else if (bid < 16578) {
    int idx = (bid - 14274) * 256 + threadIdx.x;
    int n = idx / (GK / 2);
    int kp = idx - n * (GK / 2);
    int k = kp * 2;
    u32 out = 0;
#pragma unroll
    for (int j = 0; j < 2; j++) {
      int kj = k + j;
      u16 h = 0;
      if (kj < 1500) {
        int tap = kj / 300;
        int d = kj - tap * 300;
        h = f2bf(Wmc[(size_t)n * 1500 + d * 5 + tap]);
      }
      out |= (u32)h << (16 * j);
    }
    WTmc[idx] = out;
  } else {
    int idx = (bid - 16578) * 256 + threadIdx.x;  // 600*768
    int k = idx / FNUM;
    int f = idx - k * FNUM;
    WTms[idx] = Wms[(size_t)f * 600 + k];
  }
}

// ---------------------------------------------------------------------------
// bf16 MFMA GEMM with fused relu+mean epilogue (atomicAdd into mc).
__global__ __launch_bounds__(256) void conv_gemm_kernel(
    const u16* __restrict__ A,    // [GM][GK] bf16
    const u16* __restrict__ B,    // [GN][GK] bf16 (n-major)
    const float* __restrict__ bias,
    float* __restrict__ mc) {     // [64][768]
  int bn = blockIdx.x, bm = blockIdx.y;
  __shared__ u16 As[64][72];
  __shared__ u16 Bs[64][72];
  int tid = threadIdx.x;
  int w = tid >> 6, lane = tid & 63;
  int wr = w >> 1, wc = w & 1;
  int lg = lane >> 4, lm = lane & 15;
  f32x4 acc[2][2];
#pragma unroll
  for (int i = 0; i < 2; i++)
#pragma unroll
    for (int j = 0; j < 2; j++) acc[i][j] = (f32x4)0.f;
  int c0row = tid >> 3, ck = (tid & 7) * 8;
  const u16* Ag = A + (size_t)(bm * 64) * GK;
  const u16* Bg = B + (size_t)(bn * 64) * GK;
  for (int kt = 0; kt < GK / 64; kt++) {
    int k0 = kt * 64;
    uint4 av0 = *(const uint4*)(Ag + (size_t)c0row * GK + k0 + ck);
    uint4 av1 = *(const uint4*)(Ag + (size_t)(c0row + 32) * GK + k0 + ck);
    uint4 bv0 = *(const uint4*)(Bg + (size_t)c0row * GK + k0 + ck);
    uint4 bv1 = *(const uint4*)(Bg + (size_t)(c0row + 32) * GK + k0 + ck);
    __syncthreads();
    *(uint4*)&As[c0row][ck] = av0;
    *(uint4*)&As[c0row + 32][ck] = av1;
    *(uint4*)&Bs[c0row][ck] = bv0;
    *(uint4*)&Bs[c0row + 32][ck] = bv1;
    __syncthreads();
#pragma unroll
    for (int kk = 0; kk < 2; kk++) {
      short8 af0 = *(const short8*)&As[wr * 32 + lm][kk * 32 + lg * 8];
      short8 af1 = *(const short8*)&As[wr * 32 + 16 + lm][kk * 32 + lg * 8];
      short8 bf0 = *(const short8*)&Bs[wc * 32 + lm][kk * 32 + lg * 8];
      short8 bf1 = *(const short8*)&Bs[wc * 32 + 16 + lm][kk * 32 + lg * 8];
      acc[0][0] = __builtin_amdgcn_mfma_f32_16x16x32_bf16(af0, bf0, acc[0][0], 0, 0, 0);
      acc[0][1] = __builtin_amdgcn_mfma_f32_16x16x32_bf16(af0, bf1, acc[0][1], 0, 0, 0);
      acc[1][0] = __builtin_amdgcn_mfma_f32_16x16x32_bf16(af1, bf0, acc[1][0], 0, 0, 0);
      acc[1][1] = __builtin_amdgcn_mfma_f32_16x16x32_bf16(af1, bf1, acc[1][1], 0, 0, 0);
    }
  }
#pragma unroll
  for (int mf = 0; mf < 2; mf++)
#pragma unroll
    for (int nf = 0; nf < 2; nf++) {
      int col = bn * 64 + wc * 32 + nf * 16 + lm;
      float bb = bias[col];
      int base = bm * 64 + wr * 32 + mf * 16 + lg * 4;
      int mcur = base / 46;
      float s = 0.f;
#pragma unroll
      for (int r = 0; r < 4; r++) {
        float v = fmaxf(acc[mf][nf][r] + bb, 0.f) * (1.0f / 46.0f);
        int mm = (base + r) / 46;
        if (mm != mcur) { atomicAdd(&mc[mcur * FNUM + col], s); s = 0.f; mcur = mm; }
        s += v;
      }
      atomicAdd(&mc[mcur * FNUM + col], s);
    }
}

// ---------------------------------------------------------------------------
// device bodies for the MEGA-MID kernel
__device__ __forceinline__ void conv_ms_body(
    const float* __restrict__ msg, const float* __restrict__ WT,
    const float* __restrict__ B, float* __restrict__ ms, int b) {
  int m = b / 3, fi = b - m * 3;
  int f = fi * 256 + threadIdx.x;
  const float* x = msg + m * SURF_LL * DDIM;
  float a0 = 0.f, a1 = 0.f, a2 = 0.f;
  for (int d = 0; d < DDIM; d++) {
    float v0 = x[d], v1 = x[DDIM + d], v2 = x[2 * DDIM + d], v3 = x[3 * DDIM + d];
    float wA = WT[(size_t)(2 * d) * FNUM + f];
    float wB = WT[(size_t)(2 * d + 1) * FNUM + f];
    a0 += v0 * wA + v1 * wB;
    a1 += v1 * wA + v2 * wB;
    a2 += v2 * wA + v3 * wB;
  }
  float bb = B[f];
  float r = fmaxf(a0 + bb, 0.f) + fmaxf(a1 + bb, 0.f) + fmaxf(a2 + bb, 0.f);
  ms[m * FNUM + f] = r * (1.0f / 3.0f);
}

// Fused QK^T + softmax.  K rows stride 62 (b64); Q rows stride 64 (b128
// broadcast).  Wave w computes 8 q rows x KPL k-cols/lane.
template <int DIR>
__device__ __forceinline__ void scores_body(
    const float* __restrict__ embed, const int* __restrict__ doc_vec,
    const int* __restrict__ body_vec, float* __restrict__ P, int b,
    float* __restrict__ smem) {
  constexpr int Lq = DIR ? 200 : 100;
  constexpr int Lk = DIR ? 100 : 200;
  constexpr int KPL = DIR ? 2 : 4;
  int qt = b / 80;
  int rem = b - qt * 80;
  int n = rem / 5, h = rem - n * 5;
  const int* qids = DIR ? body_vec + n * BODY_LL : doc_vec;
  const int* kids = DIR ? doc_vec : body_vec + n * BODY_LL;
  float* Ks = smem;             // [Lk][62]
  float* Qs = smem + Lk * 62;   // [32][64]
  for (int idx = threadIdx.x; idx < Lk * 15; idx += 256) {
    int r = idx / 15, c = idx - r * 15;
    float4 v = *(const float4*)(embed + (size_t)kids[r] * DDIM + h * HDIM + c * 4);
    float* dp = Ks + r * 62 + c * 4;
    dp[0] = v.x; dp[1] = v.y; dp[2] = v.z; dp[3] = v.w;
  }
  for (int idx = threadIdx.x; idx < 32 * 15; idx += 256) {
    int r = idx / 15, c = idx - r * 15;
    int q = qt * 32 + r; if (q >= Lq) q = Lq - 1;
    float4 v = *(const float4*)(embed + (size_t)qids[q] * DDIM + h * HDIM + c * 4);
    float* dp = Qs + r * 64 + c * 4;
    dp[0] = v.x; dp[1] = v.y; dp[2] = v.z; dp[3] = v.w;
  }
  __syncthreads();
  int w = threadIdx.x >> 6, lane = threadIdx.x & 63;
  int kcl[KPL];
#pragma unroll
  for (int j = 0; j < KPL; j++) {
    int kk = lane + 64 * j; kcl[j] = (kk < Lk) ? kk : (Lk - 1);
  }
  float acc[8][KPL];
#pragma unroll
  for (int i = 0; i < 8; i++)
#pragma unroll
    for (int j = 0; j < KPL; j++) acc[i][j] = 0.f;
  for (int d = 0; d < HDIM; d += 4) {
    float2 kva[KPL], kvb[KPL];
#pragma unroll
    for (int j = 0; j < KPL; j++) {
      kva[j] = *(const float2*)&Ks[kcl[j] * 62 + d];
      kvb[j] = *(const float2*)&Ks[kcl[j] * 62 + d + 2];
    }
#pragma unroll
    for (int i = 0; i < 8; i++) {
      float4 qv = *(const float4*)&Qs[(w * 8 + i) * 64 + d];
#pragma unroll
      for (int j = 0; j < KPL; j++)
        acc[i][j] += qv.x * kva[j].x + qv.y * kva[j].y +
                     qv.z * kvb[j].x + qv.w * kvb[j].y;
    }
  }
  const float scale = 0.12909944487358056f;  // 1/sqrt(60)
#pragma unroll
  for (int i = 0; i < 8; i++) {
    int q = qt * 32 + w * 8 + i;
    float mx = -1e30f;
#pragma unroll
    for (int j = 0; j < KPL; j++)
      if (lane + 64 * j < Lk) mx = fmaxf(mx, acc[i][j]);
#pragma unroll
    for (int o = 32; o >= 1; o >>= 1) mx = fmaxf(mx, __shfl_xor(mx, o));
    float mxs = mx * scale;
    float p[KPL];
    float s = 0.f;
#pragma unroll
    for (int j = 0; j < KPL; j++) {
      p[j] = (lane + 64 * j < Lk) ? __expf(acc[i][j] * scale - mxs) : 0.f;
      s += p[j];
    }
#pragma unroll
    for (int o = 32; o >= 1; o >>= 1) s += __shfl_xor(s, o);
    float inv = 1.0f / s;
    if (q < Lq) {
      float* rowp = P + (size_t)((n * 2 + DIR) * NHEADS + h) * 20000 + q * Lk;
#pragma unroll
      for (int j = 0; j < KPL; j++) {
        int kk = lane + 64 * j;
        if (kk < Lk) rowp[kk] = p[j] * inv;
      }
    }
  }
}

// tok + ctxv fused, one block per m; tokmax/p stay in LDS; cand reused for
// the final dot from LDS.
__device__ __forceinline__ void tokctxv_body(
    const float* __restrict__ candg, const float* __restrict__ ctx2g,
    float* __restrict__ local_att, int m, float* __restrict__ smem) {
  float* cand  = smem;          // [16][300]
  float* ctx   = smem + 4800;   // [16][300]
  float* tokb  = smem + 9600;   // [16][17]
  float* tkmx  = smem + 9872;   // [64] (50 used)
  float* pp    = smem + 9936;   // [64]
  float* sctxv = smem + 10000;  // [300]
  int tid = threadIdx.x;
  for (int i = tid; i < NN * DDIM; i += 256)
    cand[i] = candg[(size_t)m * NN * DDIM + i];
  int nI = tid >> 4, tt = tid & 15;
  for (int tile = 0; tile < 4; tile++) {
    int cbase = tile * 16;
    __syncthreads();
    for (int i = tid; i < 16 * DDIM; i += 256) {
      int rr = i / DDIM, cc = i - rr * DDIM;
      int t = cbase + rr;
      ctx[rr * DDIM + cc] = (t < CTX_LL) ? ctx2g[(size_t)(m * CTX_LL + t) * DDIM + cc] : 0.f;
    }
    __syncthreads();
    const float4* ca = (const float4*)(cand + nI * DDIM);
    const float4* cb = (const float4*)(ctx + tt * DDIM);
    float dsum = 0.f;
#pragma unroll
    for (int c = 0; c < 75; c++) {
      float4 a = ca[c], b = cb[c];
      dsum += a.x * b.x + a.y * b.y + a.z * b.z + a.w * b.w;
    }
    tokb[nI * 17 + tt] = dsum;
    __syncthreads();
    if (tid < 16) {
      float mx = -1e30f;
      for (int nn = 0; nn < NN; nn++) mx = fmaxf(mx, tokb[nn * 17 + tid]);
      int t = cbase + tid;
      if (t < CTX_LL) tkmx[t] = mx;
    }
  }
  __syncthreads();
  if (tid < 64) {
    float v = (tid < CTX_LL) ? tkmx[tid] : -1e30f;
    float mx = v;
#pragma unroll
    for (int o = 32; o >= 1; o >>= 1) mx = fmaxf(mx, __shfl_xor(mx, o));
    float e = (tid < CTX_LL) ? expf(v - mx) : 0.f;
    float s = e;
#pragma unroll
    for (int o = 32; o >= 1; o >>= 1) s += __shfl_xor(s, o);
    pp[tid] = e / s;
  }
  __syncthreads();
  for (int d = tid; d < DDIM; d += 256) {
    float acc = 0.f;
    for (int t = 0; t < CTX_LL; t++)
      acc += pp[t] * ctx2g[(size_t)(m * CTX_LL + t) * DDIM + d];
    sctxv[d] = acc;
  }
  __syncthreads();
  int j = tid & 15;
  float dd = 0.f;
  for (int i = j; i < DDIM; i += 16) dd += cand[nI * DDIM + i] * sctxv[i];
#pragma unroll
  for (int o = 8; o >= 1; o >>= 1) dd += __shfl_xor(dd, o);
  if (j == 0) local_att[m * NN + nI] = dd;
}

// MEGA-MID: [0,192) conv_ms ; [192,512) scores dir0 ; [512,1072) scores dir1 ;
// [1072,1136) tok+ctxv.  Unified smem 14448 floats (57.8 KB, 2 blocks/CU).
__global__ __launch_bounds__(256) void mega_mid_kernel(
    const float* __restrict__ embed,
    const int* __restrict__ doc_vec,
    const int* __restrict__ body_vec,
    const float* __restrict__ msg,
    const float* __restrict__ WTms,
    const float* __restrict__ Bms,
    const float* __restrict__ candg,
    const float* __restrict__ ctx2g,
    float* __restrict__ ms,
    float* __restrict__ P,
    float* __restrict__ local_att) {
  __shared__ float smem[14448];
  int bid = blockIdx.x;
  if (bid < 192) {
    conv_ms_body(msg, WTms, Bms, ms, bid);
  } else if (bid < 512) {
    scores_body<0>(embed, doc_vec, body_vec, P, bid - 192, smem);
  } else if (bid < 1072) {
    scores_body<1>(embed, doc_vec, body_vec, P, bid - 512, smem);
  } else {
    tokctxv_body(candg, ctx2g, local_att, bid - 1072, smem);
  }
}

// ---------------------------------------------------------------------------
// PV + max-pool over q, both dirs merged.
__global__ __launch_bounds__(256) void attn_pv_kernel(
    const float* __restrict__ embed,
    const int* __restrict__ doc_vec,
    const int* __restrict__ body_vec,
    const float* __restrict__ P,
    float* __restrict__ pv0,   // [16][5][2][60]
    float* __restrict__ pv1) { // [16][5][4][60]
  int bid = blockIdx.x;
  int dir, pt, n, h;
  if (bid < 160) { dir = 0; h = bid % 5; n = (bid / 5) % 16; pt = bid / 80; }
  else { int b = bid - 160; dir = 1; h = b % 5; n = (b / 5) % 16; pt = b / 80; }
  int Lq = dir ? 200 : 100;
  int Lk = dir ? 100 : 200;
  int Lk4 = Lk >> 2;
  int K4STR = dir ? 27 : 51;
  const int* kids = dir ? doc_vec : body_vec + n * BODY_LL;
  __shared__ float4 Kt4[60 * 51];
  __shared__ float red[4][64];
  float* Ktf = (float*)Kt4;
  int RS = K4STR * 4;
  for (int idx = threadIdx.x; idx < Lk * 15; idx += 256) {
    int r = idx / 15, c = idx - r * 15;
    float4 v = *(const float4*)(embed + (size_t)kids[r] * DDIM + h * HDIM + c * 4);
    Ktf[(c * 4 + 0) * RS + r] = v.x;
    Ktf[(c * 4 + 1) * RS + r] = v.y;
    Ktf[(c * 4 + 2) * RS + r] = v.z;
    Ktf[(c * 4 + 3) * RS + r] = v.w;
  }
  __syncthreads();
  int lane = threadIdx.x & 63;
  int w = __builtin_amdgcn_readfirstlane(threadIdx.x >> 6);
  int dl = (lane < HDIM) ? lane : (HDIM - 1);
  const float4* Krow = Kt4 + dl * K4STR;
  const float* Pb = P + (size_t)((n * 2 + dir) * NHEADS + h) * 20000;
  float omax = -1e30f;
#pragma unroll
  for (int p = 0; p < 4; p++) {
    int q0 = pt * 64 + p * 16 + w * 4;
    int qa0 = min(q0, Lq - 1), qa1 = min(q0 + 1, Lq - 1);
    int qa2 = min(q0 + 2, Lq - 1), qa3 = min(q0 + 3, Lq - 1);
    const float4* P0 = (const float4*)(Pb + (size_t)qa0 * Lk);
    const float4* P1 = (const float4*)(Pb + (size_t)qa1 * Lk);
    const float4* P2 = (const float4*)(Pb + (size_t)qa2 * Lk);
    const float4* P3 = (const float4*)(Pb + (size_t)qa3 * Lk);
    float o0 = 0.f, o1 = 0.f, o2 = 0.f, o3 = 0.f;
    for (int k4 = 0; k4 < Lk4; k4++) {
      float4 pp0 = P0[k4], pp1 = P1[k4], pp2 = P2[k4], pp3 = P3[k4];
      float4 kk = Krow[k4];
      o0 += pp0.x * kk.x + pp0.y * kk.y + pp0.z * kk.z + pp0.w * kk.w;
      o1 += pp1.x * kk.x + pp1.y * kk.y + pp1.z * kk.z + pp1.w * kk.w;
      o2 += pp2.x * kk.x + pp2.y * kk.y + pp2.z * kk.z + pp2.w * kk.w;
      o3 += pp3.x * kk.x + pp3.y * kk.y + pp3.z * kk.z + pp3.w * kk.w;
    }
    if (q0 < Lq)     omax = fmaxf(omax, o0);
    if (q0 + 1 < Lq) omax = fmaxf(omax, o1);
    if (q0 + 2 < Lq) omax = fmaxf(omax, o2);
    if (q0 + 3 < Lq) omax = fmaxf(omax, o3);
  }
  red[threadIdx.x >> 6][lane] = omax;
  __syncthreads();
  if (threadIdx.x < 64 && lane < HDIM) {
    float m4 = fmaxf(fmaxf(red[0][lane], red[1][lane]),
                     fmaxf(red[2][lane], red[3][lane]));
    float* dst = dir ? pv1 + (size_t)((n * NHEADS + h) * 4 + pt) * HDIM
                     : pv0 + (size_t)((n * NHEADS + h) * 2 + pt) * HDIM;
    dst[lane] = m4;
  }
}

// ---------------------------------------------------------------------------
__global__ __launch_bounds__(256) void mlp_kernel(
    const float* __restrict__ pv0, const float* __restrict__ pv1,
    const float* __restrict__ w1, const float* __restrict__ b1,
    const float* __restrict__ w2, const float* __restrict__ b2,
    float* __restrict__ att_score) {
  int n = blockIdx.x, tid = threadIdx.x;
  __shared__ float comb[600];
  for (int idx = tid; idx < 300; idx += 256) {
    int h = idx / 60, d = idx - h * 60;
    float mx = -1e30f;
#pragma unroll
    for (int pt = 0; pt < 2; pt++)
      mx = fmaxf(mx, pv0[(size_t)((n * NHEADS + h) * 2 + pt) * HDIM + d]);
    comb[idx] = mx;
    mx = -1e30f;
#pragma unroll
    for (int pt = 0; pt < 4; pt++)
      mx = fmaxf(mx, pv1[(size_t)((n * NHEADS + h) * 4 + pt) * HDIM + d]);
    comb[300 + idx] = mx;
  }
  __syncthreads();
  float partial = 0.f;
  for (int j = tid; j < 300; j += 256) {
    float hh = b1[j];
    for (int k = 0; k < 600; k++) hh += comb[k] * w1[k * 300 + j];
    partial += fmaxf(hh, 0.f) * w2[j];
  }
  __shared__ float redd[256];
  redd[tid] = partial;
  __syncthreads();
  for (int s = 128; s > 0; s >>= 1) {
    if (tid < s) redd[tid] += redd[tid + s];
    __syncthreads();
  }
  if (tid == 0) att_score[n] = 1.0f / (1.0f + expf(-(redd[0] + b2[0])));
}

// ---------------------------------------------------------------------------
__global__ __launch_bounds__(256) void final_kernel(
    const float* __restrict__ ms,
    const float* __restrict__ mc,
    const float* __restrict__ title,
    const float* __restrict__ bert,
    const float* __restrict__ att_score,
    const float* __restrict__ m2c_prior,
    const float* __restrict__ hand,
    const float* __restrict__ local_att,
    const float* __restrict__ w7,
    const float* __restrict__ b7,
    float* __restrict__ out) {
  int m = blockIdx.x, tid = threadIdx.x;
  __shared__ float sms[FNUM], smc[FNUM], smd[FNUM];
  __shared__ float snorm[3], sscore[16], wred[3][4];
  for (int i = tid; i < FNUM; i += 256) {
    sms[i] = ms[m * FNUM + i];
    smc[i] = mc[m * FNUM + i];
    smd[i] = bert[i];
  }
  __syncthreads();
  float p1 = 0.f, p2 = 0.f, p3 = 0.f;
  for (int i = tid; i < FNUM; i += 256) {
    float a = sms[i], b = smc[i], c = smd[i];
    p1 += a * a; p2 += b * b; p3 += c * c;
  }
#pragma unroll
  for (int o = 32; o >= 1; o >>= 1) {
    p1 += __shfl_xor(p1, o); p2 += __shfl_xor(p2, o); p3 += __shfl_xor(p3, o);
  }
  int wid = tid >> 6, lane = tid & 63;
  if (lane == 0) { wred[0][wid] = p1; wred[1][wid] = p2; wred[2][wid] = p3; }
  __syncthreads();
  if (tid == 0) {
    snorm[0] = fmaxf(sqrtf(wred[0][0] + wred[0][1] + wred[0][2] + wred[0][3]), 1e-6f);
    snorm[1] = fmaxf(sqrtf(wred[1][0] + wred[1][1] + wred[1][2] + wred[1][3]), 1e-6f);
    snorm[2] = fmaxf(sqrtf(wred[2][0] + wred[2][1] + wred[2][2] + wred[2][3]), 1e-6f);
  }
  __syncthreads();
  int nI = tid >> 4, j = tid & 15;
  float d1 = 0.f, d2 = 0.f, d3 = 0.f, d4 = 0.f;
  for (int i = j; i < FNUM; i += 16) {
    float t = title[nI * FNUM + i];
    d1 += sms[i] * t; d2 += smc[i] * t; d3 += smd[i] * t; d4 += t * t;
  }
#pragma unroll
  for (int o = 8; o >= 1; o >>= 1) {
    d1 += __shfl_xor(d1, o); d2 += __shfl_xor(d2, o);
    d3 += __shfl_xor(d3, o); d4 += __shfl_xor(d4, o);
  }
  if (j == 0) {
    float nt = fmaxf(sqrtf(d4), 1e-6f);
    float cos_st = d1 / (snorm[0] * nt);
    float cos_ct = d2 / (snorm[1] * nt);
    float cos_dt = d3 / (snorm[2] * nt);
    float score = hand[nI] * w7[0] + m2c_prior[nI] * w7[1] +
                  local_att[m * NN + nI] * w7[2] + att_score[nI] * w7[3] +
                  cos_st * w7[4] + cos_dt * w7[5] + cos_ct * w7[6] + b7[0];
    sscore[nI] = score;
  }
  __syncthreads();
  if (tid < 16) {
    float x = sscore[tid];
    float s = x;
#pragma unroll
    for (int o = 8; o >= 1; o >>= 1) s += __shfl_xor(s, o);
    float mu = s * (1.0f / 16.0f);
    float dv = (x - mu) * (x - mu);
    float vs = dv;
#pragma unroll
    for (int o = 8; o >= 1; o >>= 1) vs += __shfl_xor(vs, o);
    float sd = sqrtf(vs * (1.0f / 15.0f));
    float z = (x - mu) / sd;
    float zm = z;
#pragma unroll
    for (int o = 8; o >= 1; o >>= 1) zm = fmaxf(zm, __shfl_xor(zm, o));
    float e = expf(z - zm);
    float es = e;
#pragma unroll
    for (int o = 8; o >= 1; o >>= 1) es += __shfl_xor(es, o);
    float sm = e / es;
    float zmin = z;
#pragma unroll
    for (int o = 8; o >= 1; o >>= 1) zmin = fminf(zmin, __shfl_xor(zmin, o));
    float u0 = (z + 1.0f - zmin) / (zm - zmin);
    float us = u0;
#pragma unroll
    for (int o = 8; o >= 1; o >>= 1) us += __shfl_xor(us, o);
    float u = u0 / us;
    out[m * NN + tid] = z;
    out[MM * NN + m * NN + tid] = sm;
    out[2 * MM * NN + m * NN + tid] = u;
  }
}

// ---------------------------------------------------------------------------
extern "C" void kernel_launch(void* const* d_in, const int* in_sizes, int n_in,
                              void* d_out, int out_size, void* d_ws, size_t ws_size,
                              hipStream_t stream) {
  const int*   mention_vec   = (const int*)d_in[3];
  const int*   context_vec   = (const int*)d_in[4];
  const int*   doc_vec       = (const int*)d_in[5];
  const float* title_vec     = (const float*)d_in[6];
  const int*   body_vec      = (const int*)d_in[7];
  const float* m2c_prior     = (const float*)d_in[9];
  const int*   men2cands     = (const int*)d_in[10];
  const int*   contexts_ids  = (const int*)d_in[11];
  const float* hand_features = (const float*)d_in[12];
  const float* bert_doc_vec  = (const float*)d_in[13];
  const float* embed_table   = (const float*)d_in[14];
  const float* conv_ms_w     = (const float*)d_in[15];
  const float* conv_ms_b     = (const float*)d_in[16];
  const float* conv_mc_w     = (const float*)d_in[17];
  const float* conv_mc_b     = (const float*)d_in[18];
  const float* layer_local_w = (const float*)d_in[19];
  const float* layer_local_b = (const float*)d_in[20];
  const float* att_w1        = (const float*)d_in[21];
  const float* att_b1        = (const float*)d_in[22];
  const float* att_w2        = (const float*)d_in[23];
  const float* att_b2        = (const float*)d_in[24];

  float* ws     = (float*)d_ws;
  float* msg    = ws + OFF_MSG;
  float* ctx2g  = ws + OFF_CTX2G;
  float* candg  = ws + OFF_CANDG;
  float* ms     = ws + OFF_MS;
  float* mc     = ws + OFF_MC;
  float* pv0    = ws + OFF_PV0;
  float* pv1    = ws + OFF_PV1;
  float* att_sc = ws + OFF_ASC;
  float* latt   = ws + OFF_LATT;
  u16*   Abf    = (u16*)(ws + OFF_ABF);
  u16*   WTmc   = (u16*)(ws + OFF_WTMC);
  float* WTms   = ws + OFF_WTMS;
  float* P      = ws + OFF_P;
  float* out    = (float*)d_out;

  mega_prep_kernel<<<dim3(18378), dim3(256), 0, stream>>>(
      embed_table, mention_vec, context_vec, contexts_ids, men2cands,
      conv_mc_w, conv_ms_w, ws, mc, (u32*)Abf, (u32*)WTmc, WTms);
  conv_gemm_kernel<<<dim3(GN / 64, GM / 64), dim3(256), 0, stream>>>(
      Abf, WTmc, conv_mc_b, mc);
  mega_mid_kernel<<<dim3(1136), dim3(256), 0, stream>>>(
      embed_table, doc_vec, body_vec, msg, WTms, conv_ms_b, candg, ctx2g,
      ms, P, latt);
  attn_pv_kernel<<<dim3(480), dim3(256), 0, stream>>>(
      embed_table, doc_vec, body_vec, P, pv0, pv1);
  mlp_kernel<<<dim3(NN), dim3(256), 0, stream>>>(pv0, pv1, att_w1, att_b1, att_w2, att_b2, att_sc);
  final_kernel<<<dim3(MM), dim3(256), 0, stream>>>(
      ms, mc, title_vec, bert_doc_vec, att_sc, m2c_prior, hand_features,
      latt, layer_local_w, layer_local_b, out);
}